// Round 3
// baseline (1196.884 us; speedup 1.0000x reference)
//
#include <hip/hip_runtime.h>
#include <hip/hip_bf16.h>

typedef __attribute__((ext_vector_type(8))) short short8;
typedef __attribute__((ext_vector_type(4))) float f32x4;
typedef unsigned short ushort_t;

#define BM 128
#define BN 128
#define BK 64

__device__ __forceinline__ ushort_t f2bf_rne(float f) {
    unsigned u = __float_as_uint(f);
    u += 0x7FFF + ((u >> 16) & 1);   // round-to-nearest-even
    return (ushort_t)(u >> 16);
}

__device__ __forceinline__ short8 pack8(float4 a, float4 b) {
    short8 r;
    r[0] = (short)f2bf_rne(a.x); r[1] = (short)f2bf_rne(a.y);
    r[2] = (short)f2bf_rne(a.z); r[3] = (short)f2bf_rne(a.w);
    r[4] = (short)f2bf_rne(b.x); r[5] = (short)f2bf_rne(b.y);
    r[6] = (short)f2bf_rne(b.z); r[7] = (short)f2bf_rne(b.w);
    return r;
}

// Per-row expectation of quantum outcomes: one wave per row, 4 rows/block.
// int4-vectorized loads (shots=1000 -> 250 int4, 16B-aligned: 4000B rows).
__global__ void expect_kernel(const int* __restrict__ q, float* __restrict__ e,
                              int rows, int shots) {
    int row = blockIdx.x * (blockDim.x >> 6) + (threadIdx.x >> 6);
    int lane = threadIdx.x & 63;
    if (row >= rows) return;
    const int4* rp4 = (const int4*)(q + (long long)row * shots);
    int nvec = shots >> 2;                 // 250
    int s = 0;
    for (int j = lane; j < nvec; j += 64) {
        int4 v = rp4[j];
        s += v.x + v.y + v.z + v.w;
    }
    #pragma unroll
    for (int off = 32; off; off >>= 1) s += __shfl_down(s, off, 64);
    if (lane == 0) e[row] = (float)s * (1.0f / (1000.0f * 15.0f));
}

// ---------------------------------------------------------------------------
// ROUND-7 (= R6 resubmit; R6 failed on container acquisition, not the kernel).
// Fused-conversion GEMM as the primary path: fp32 A/B tiles load to VGPRs,
// pack to bf16 (RNE, identical rounding to the old prep pass), write to
// XOR-swizzled LDS during staging. The separate prep dispatch (~270us,
// layout-insensitive per R5 null result) is deleted.
// Costs: reg-staging instead of global_load_lds (m151: -26% staging-bound)
// + 2x fetch bytes (fp32), but x+W fp32 = 192MB < 256MB LLC -> L3-absorbed.
// Saves: entire 192MB-read + 96MB-write prep dispatch.
// NT-GEMM: C[m,n] = sum_k A[m,k]*B[n,k] + bias[n] + expect[m], fp32 out.
// m97 structure, XOR-swizzled LDS (0 bank conflicts), XCD-aware block map.
// ---------------------------------------------------------------------------
__global__ __launch_bounds__(256, 2)
void gemm_fused_kernel(const float* __restrict__ A, const float* __restrict__ B,
                       const float* __restrict__ bias, const float* __restrict__ expect,
                       float* __restrict__ C, int M, int N, int K) {
    __shared__ ushort_t As[BM * BK];   // 16 KB
    __shared__ ushort_t Bs[BN * BK];   // 16 KB

    // XCD-aware mapping: N/BN = 32 = 8 XCDs * 4 strips; M/BM = 64.
    int pid = blockIdx.x;
    const int xcd = pid & 7;
    const int p   = pid >> 3;            // 0..255 per XCD
    int pid_n = xcd * 4 + (p & 3);       // 4-N-block strip owned by this XCD
    int pid_m = p >> 2;                  // sweeps M; A-strip reused 4x in a row

    const int tid  = threadIdx.x;
    const int lane = tid & 63;
    const int wave = tid >> 6;
    const int wm = (wave >> 1) * 64;
    const int wn = (wave & 1) * 64;

    // staging: thread (srow, chalf) covers 4 of the 8 16B-chunks of its row.
    // chunk c of row r is stored at LDS slot (c ^ (r&7)) -- same swizzle the
    // read side (q ^ rlow) expects; measured 0 bank conflicts.
    const int srow = tid >> 1;                 // 0..127
    const int chalf = (tid & 1) * 4;           // first 8-float chunk this thread packs

    const float* a_base = A + ((long long)pid_m * BM + srow) * K + chalf * 8;
    const float* b_base = B + ((long long)pid_n * BN + srow) * K + chalf * 8;

    f32x4 acc[4][4];
    #pragma unroll
    for (int i = 0; i < 4; i++)
        #pragma unroll
        for (int j = 0; j < 4; j++)
            acc[i][j] = (f32x4)(0.0f);

    const int quad = lane >> 4;
    const int l15  = lane & 15;
    const int rlow = l15 & 7;

    for (int k0 = 0; k0 < K; k0 += BK) {
        {
            const float4* ap = (const float4*)(a_base + k0);
            const float4* bp = (const float4*)(b_base + k0);
            float4 fa[8], fb[8];
            #pragma unroll
            for (int c = 0; c < 8; c++) { fa[c] = ap[c]; fb[c] = bp[c]; }
            #pragma unroll
            for (int c = 0; c < 4; c++) {
                int sl = ((chalf + c) ^ (srow & 7)) * 8;   // swizzled 16B slot
                *(short8*)(As + srow * BK + sl) = pack8(fa[2*c], fa[2*c+1]);
                *(short8*)(Bs + srow * BK + sl) = pack8(fb[2*c], fb[2*c+1]);
            }
        }
        __syncthreads();

        #pragma unroll
        for (int ks = 0; ks < 2; ks++) {
            int q = ks * 4 + quad;                  // global chunk index
            int sw = (q ^ rlow) * 8;                // swizzled LDS offset
            short8 af[4], bf[4];
            #pragma unroll
            for (int i = 0; i < 4; i++) {
                af[i] = *(const short8*)(As + (wm + i * 16 + l15) * BK + sw);
                bf[i] = *(const short8*)(Bs + (wn + i * 16 + l15) * BK + sw);
            }
            #pragma unroll
            for (int i = 0; i < 4; i++)
                #pragma unroll
                for (int j = 0; j < 4; j++)
                    acc[i][j] = __builtin_amdgcn_mfma_f32_16x16x32_bf16(
                        af[i], bf[j], acc[i][j], 0, 0, 0);
        }
        __syncthreads();
    }

    // epilogue: C/D layout col = lane&15, row = quad*4 + reg  [m89-verified]
    long long row0 = (long long)pid_m * BM + wm;
    int col0 = pid_n * BN + wn;
    #pragma unroll
    for (int j = 0; j < 4; j++) {
        int col = col0 + j * 16 + l15;
        float bj = bias[col];
        #pragma unroll
        for (int i = 0; i < 4; i++) {
            #pragma unroll
            for (int r = 0; r < 4; r++) {
                long long row = row0 + i * 16 + quad * 4 + r;
                C[row * N + col] = acc[i][j][r] + bj + expect[row];
            }
        }
    }
}

extern "C" void kernel_launch(void* const* d_in, const int* in_sizes, int n_in,
                              void* d_out, int out_size, void* d_ws, size_t ws_size,
                              hipStream_t stream) {
    const float* x = (const float*)d_in[0];   // [8192, 4096] fp32
    const float* W = (const float*)d_in[1];   // [4096, 4096] fp32
    const float* b = (const float*)d_in[2];   // [4096] fp32
    const int*   q = (const int*)d_in[3];     // [8192, 1000] int32
    float* out = (float*)d_out;               // [8192, 4096] fp32

    const int M = 8192, N = 4096, K = 4096, SHOTS = 1000;

    float* expect = (float*)d_ws;             // 32 KB

    expect_kernel<<<M / 4, 256, 0, stream>>>(q, expect, M, SHOTS);
    gemm_fused_kernel<<<(M / BM) * (N / BN), 256, 0, stream>>>(x, W, b, expect, out, M, N, K);
}

// Round 4
// 517.679 us; speedup vs baseline: 2.3120x; 2.3120x over previous
//
#include <hip/hip_runtime.h>
#include <hip/hip_bf16.h>

typedef __attribute__((ext_vector_type(8))) short short8;
typedef __attribute__((ext_vector_type(4))) float f32x4;
typedef unsigned short ushort_t;

// ---------------- prep (two-pass, proven R0/R1 @ ~140us) ----------------

__device__ __forceinline__ ushort_t f2bf_rne(float f) {
    unsigned u = __float_as_uint(f);
    u += 0x7FFF + ((u >> 16) & 1);   // round-to-nearest-even
    return (ushort_t)(u >> 16);
}

__device__ __forceinline__ unsigned pack2(float lo, float hi) {
    unsigned a = __float_as_uint(lo);
    a += 0x7FFF + ((a >> 16) & 1);
    unsigned b = __float_as_uint(hi);
    b += 0x7FFF + ((b >> 16) & 1);
    return (a >> 16) | (b & 0xFFFF0000u);
}

__device__ __forceinline__ short8 pack8(float4 a, float4 b) {
    short8 r;
    r[0] = (short)f2bf_rne(a.x); r[1] = (short)f2bf_rne(a.y);
    r[2] = (short)f2bf_rne(a.z); r[3] = (short)f2bf_rne(a.w);
    r[4] = (short)f2bf_rne(b.x); r[5] = (short)f2bf_rne(b.y);
    r[6] = (short)f2bf_rne(b.z); r[7] = (short)f2bf_rne(b.w);
    return r;
}

// fp32 -> bf16, 16 floats/thread, lane-contiguous loads/stores.
// Split from the old fused prep so rocprof reports its counters separately.
__global__ void conv_kernel(const float* __restrict__ src, ushort_t* __restrict__ dst) {
    long long base = (long long)blockIdx.x * 1024;
    const float4* s4 = (const float4*)src;
    uint2* d2 = (uint2*)dst;
    #pragma unroll
    for (int c = 0; c < 4; c++) {
        long long idx = base + c * 256 + threadIdx.x;
        float4 a = s4[idx];
        uint2 r;
        r.x = pack2(a.x, a.y);
        r.y = pack2(a.z, a.w);
        d2[idx] = r;
    }
}

// per-row expectation: one wave per row, 4 rows/block, int4 loads.
__global__ void expect_kernel(const int* __restrict__ q, float* __restrict__ e,
                              int rows, int shots) {
    int row = blockIdx.x * (blockDim.x >> 6) + (threadIdx.x >> 6);
    int lane = threadIdx.x & 63;
    if (row >= rows) return;
    const int4* rp4 = (const int4*)(q + (long long)row * shots);
    int nvec = shots >> 2;                 // 250
    int s = 0;
    for (int j = lane; j < nvec; j += 64) {
        int4 v = rp4[j];
        s += v.x + v.y + v.z + v.w;
    }
    #pragma unroll
    for (int off = 32; off; off >>= 1) s += __shfl_down(s, off, 64);
    if (lane == 0) e[row] = (float)s * (1.0f / (1000.0f * 15.0f));
}

// ---------------------------------------------------------------------------
// ROUND-8: 256x256 8-phase counted-vmcnt GEMM (T2+T3+T4+T5 port, plain HIP).
// 8 waves (2M x 4N), BK=64, LDS [2buf][2khalf][256][32] bf16 = 128 KiB.
// K-half regions give lane-linear LDS dests for global_load_lds while
// consumption staggers by k-half -> per-wave s_waitcnt vmcnt(4) twice per
// K-tile, NEVER 0 in the main loop. Raw s_barrier (no compiler vmcnt(0)
// drain). Slot XOR-swizzle (quad ^ ((l15>>1)&3)): <=2-way bank alias = free.
// setprio(1) around each 16-MFMA cluster (T5; needs the phase role-split).
// Per-K-tile accumulation order (kh0 then kh1) identical to the proven
// 128^2 kernel -> same numerics.
// C[m,n] = sum_k A[m,k]*B[n,k] + bias[n] + expect[m], fp32 out.
// ---------------------------------------------------------------------------

#define GLDS(srcp, dstp) \
    __builtin_amdgcn_global_load_lds( \
        (const __attribute__((address_space(1))) unsigned int*)(srcp), \
        (__attribute__((address_space(3))) unsigned int*)(dstp), 16, 0, 0)

#define BAR() do { asm volatile("" ::: "memory"); \
                   __builtin_amdgcn_s_barrier(); \
                   asm volatile("" ::: "memory"); } while (0)

#define VMCNT(n) asm volatile("s_waitcnt vmcnt(" #n ")" ::: "memory")

#define PH_READ_A(kh) do { \
    const ushort_t* At = As + ((b * 2 + (kh)) << 13); \
    _Pragma("unroll") \
    for (int i = 0; i < 8; i++) af[i] = *(const short8*)(At + rdA0 + (i << 9)); \
} while (0)

#define PH_READ_B(kh, nh) do { \
    const ushort_t* Bt = Bs + ((b * 2 + (kh)) << 13); \
    bfr[0] = *(const short8*)(Bt + rdB0 + ((nh) << 10)); \
    bfr[1] = *(const short8*)(Bt + rdB0 + ((nh) << 10) + 512); \
} while (0)

#define PH_MFMA(nh) do { \
    __builtin_amdgcn_s_setprio(1); \
    _Pragma("unroll") \
    for (int i = 0; i < 8; i++) { \
        acc[i][(nh) * 2]     = __builtin_amdgcn_mfma_f32_16x16x32_bf16(af[i], bfr[0], acc[i][(nh) * 2], 0, 0, 0); \
        acc[i][(nh) * 2 + 1] = __builtin_amdgcn_mfma_f32_16x16x32_bf16(af[i], bfr[1], acc[i][(nh) * 2 + 1], 0, 0, 0); \
    } \
    __builtin_amdgcn_s_setprio(0); \
} while (0)

__global__ __launch_bounds__(512, 2)
void gemm8_kernel(const ushort_t* __restrict__ A, const ushort_t* __restrict__ B,
                  const float* __restrict__ bias, const float* __restrict__ expect,
                  float* __restrict__ C, int M, int N, int K) {
    __shared__ ushort_t As[2 * 2 * 256 * 32];   // 64 KB: [buf][kh][row 256][k 32]
    __shared__ ushort_t Bs[2 * 2 * 256 * 32];   // 64 KB

    // XCD-aware mapping: 512 blocks = 8 XCDs x 64; N/256 = 16 strips -> 2/XCD,
    // A-tile reused 2x back-to-back within an XCD (p pairs share pid_m).
    const int pid = blockIdx.x;
    const int xcd = pid & 7;
    const int p   = pid >> 3;              // 0..63
    const int pid_n = xcd * 2 + (p & 1);   // 0..15
    const int pid_m = p >> 1;              // 0..31

    const int tid  = threadIdx.x;
    const int lane = tid & 63;
    const int wave = tid >> 6;             // 0..7
    const int wr = wave >> 2;              // 0..1  (M half)
    const int wc = wave & 3;               // 0..3  (N quarter)
    const int quad = lane >> 4;
    const int l15  = lane & 15;

    // read-side swizzled slot: quad ^ ((l15>>1)&3)  (constant per lane for ALL
    // frags: row low bits 1-2 come only from l15)
    const int rslot = (quad ^ ((l15 >> 1) & 3)) * 8;              // elements
    const int rdA0 = (wr * 128 + l15) * 32 + rslot;               // + i*512
    const int rdB0 = (wc * 64 + l15) * 32 + rslot;                // + nh*1024 + j*512

    // stage-side: thread covers chunk d = L*512+tid; r=d>>2, sl=d&3;
    // source chunk c = sl ^ ((r>>1)&3)  (L-independent). Dest = region + tid*16B.
    const int srow0 = tid >> 2;                                   // 0..127
    const int ssl   = tid & 3;
    const int sc    = ssl ^ ((srow0 >> 1) & 3);

    const ushort_t* aS0 = A + ((long long)pid_m * 256 + srow0) * K + sc * 8;
    const ushort_t* aS1 = aS0 + 128LL * K;
    const ushort_t* bS0 = B + ((long long)pid_n * 256 + srow0) * K + sc * 8;
    const ushort_t* bS1 = bS0 + 128LL * K;

    f32x4 acc[8][4];
    #pragma unroll
    for (int i = 0; i < 8; i++)
        #pragma unroll
        for (int j = 0; j < 4; j++)
            acc[i][j] = (f32x4)(0.0f);

    const int NT = K / 64;                 // 64 K-tiles

    // ---- prologue: stage tile 0 into buf 0 (order A0,B0,A1,B1), drain ----
    GLDS(aS0,      As + tid * 8);
    GLDS(aS1,      As + tid * 8 + 4096);
    GLDS(bS0,      Bs + tid * 8);
    GLDS(bS1,      Bs + tid * 8 + 4096);
    GLDS(aS0 + 32, As + (1 << 13) + tid * 8);
    GLDS(aS1 + 32, As + (1 << 13) + tid * 8 + 4096);
    GLDS(bS0 + 32, Bs + (1 << 13) + tid * 8);
    GLDS(bS1 + 32, Bs + (1 << 13) + tid * 8 + 4096);
    VMCNT(0);
    BAR();

    short8 af[8], bfr[2];

    // ---- main loop: compute tile t from buf b, stage tile t+1 into buf b^1.
    // vmcnt(4) at end of P1 (guarantees kh1(t) landed for P2) and end of P3
    // (guarantees kh0(t+1) landed for next P0). 4 loads always in flight.
    for (int t = 0; t < NT - 1; ++t) {
        const int b  = t & 1;
        const int bn = b ^ 1;
        const long long k1 = (long long)(t + 1) * 64;
        ushort_t* An0 = As + ((bn * 2 + 0) << 13) + tid * 8;
        ushort_t* An1 = As + ((bn * 2 + 1) << 13) + tid * 8;
        ushort_t* Bn0 = Bs + ((bn * 2 + 0) << 13) + tid * 8;
        ushort_t* Bn1 = Bs + ((bn * 2 + 1) << 13) + tid * 8;

        // P0: kh0, nh0 + stage A-kh0(t+1)
        PH_READ_A(0);
        PH_READ_B(0, 0);
        GLDS(aS0 + k1, An0);
        GLDS(aS1 + k1, An0 + 4096);
        BAR();
        PH_MFMA(0);
        BAR();

        // P1: kh0, nh1 (af reused) + stage B-kh0(t+1)
        PH_READ_B(0, 1);
        GLDS(bS0 + k1, Bn0);
        GLDS(bS1 + k1, Bn0 + 4096);
        BAR();
        PH_MFMA(1);
        VMCNT(4);
        BAR();

        // P2: kh1, nh0 + stage A-kh1(t+1)
        PH_READ_A(1);
        PH_READ_B(1, 0);
        GLDS(aS0 + k1 + 32, An1);
        GLDS(aS1 + k1 + 32, An1 + 4096);
        BAR();
        PH_MFMA(0);
        BAR();

        // P3: kh1, nh1 + stage B-kh1(t+1)
        PH_READ_B(1, 1);
        GLDS(bS0 + k1 + 32, Bn1);
        GLDS(bS1 + k1 + 32, Bn1 + 4096);
        BAR();
        PH_MFMA(1);
        VMCNT(4);
        BAR();
    }

    // ---- epilogue tile NT-1 (no staging; drain remaining 4 before kh1) ----
    {
        const int b = (NT - 1) & 1;
        PH_READ_A(0);
        PH_READ_B(0, 0);
        BAR();
        PH_MFMA(0);
        BAR();
        PH_READ_B(0, 1);
        BAR();
        PH_MFMA(1);
        VMCNT(0);
        BAR();
        PH_READ_A(1);
        PH_READ_B(1, 0);
        BAR();
        PH_MFMA(0);
        BAR();
        PH_READ_B(1, 1);
        BAR();
        PH_MFMA(1);
    }

    // ---- C write: col = l15, row = quad*4 + reg [m89-verified] ----
    long long row0 = (long long)pid_m * 256 + wr * 128;
    int col0 = pid_n * 256 + wc * 64;
    float bj[4];
    #pragma unroll
    for (int j = 0; j < 4; j++) bj[j] = bias[col0 + j * 16 + l15];
    #pragma unroll
    for (int i = 0; i < 8; i++) {
        #pragma unroll
        for (int rr = 0; rr < 4; rr++) {
            long long row = row0 + i * 16 + quad * 4 + rr;
            float er = expect[row];
            float* Crow = C + row * (long long)N;
            #pragma unroll
            for (int j = 0; j < 4; j++)
                Crow[col0 + j * 16 + l15] = acc[i][j][rr] + bj[j] + er;
        }
    }
}

// ---------------------------------------------------------------------------
// Fallback (small ws): proven 128^2 f32-staging GEMM (R1).
// ---------------------------------------------------------------------------
#define BM 128
#define BN 128
#define BK 64

__global__ __launch_bounds__(256, 2)
void gemm_f32stage_kernel(const float* __restrict__ A, const float* __restrict__ B,
                          const float* __restrict__ bias, const float* __restrict__ expect,
                          float* __restrict__ C, int M, int N, int K) {
    __shared__ ushort_t As[BM * BK];
    __shared__ ushort_t Bs[BN * BK];

    int pid = blockIdx.x;
    const int xcd = pid & 7;
    const int p   = pid >> 3;
    int pid_n = xcd * 4 + (p & 3);
    int pid_m = p >> 2;

    const int tid  = threadIdx.x;
    const int lane = tid & 63;
    const int wave = tid >> 6;
    const int wm = (wave >> 1) * 64;
    const int wn = (wave & 1) * 64;

    const int srow = tid >> 1;
    const int chalf = (tid & 1) * 4;

    const float* a_base = A + ((long long)pid_m * BM + srow) * K + chalf * 8;
    const float* b_base = B + ((long long)pid_n * BN + srow) * K + chalf * 8;

    f32x4 acc[4][4];
    #pragma unroll
    for (int i = 0; i < 4; i++)
        #pragma unroll
        for (int j = 0; j < 4; j++)
            acc[i][j] = (f32x4)(0.0f);

    const int quad = lane >> 4;
    const int l15  = lane & 15;
    const int rlow = l15 & 7;

    for (int k0 = 0; k0 < K; k0 += BK) {
        {
            const float4* ap = (const float4*)(a_base + k0);
            const float4* bp = (const float4*)(b_base + k0);
            float4 fa[8], fb[8];
            #pragma unroll
            for (int c = 0; c < 8; c++) { fa[c] = ap[c]; fb[c] = bp[c]; }
            #pragma unroll
            for (int c = 0; c < 4; c++) {
                int sl = ((chalf + c) ^ (srow & 7)) * 8;
                *(short8*)(As + srow * BK + sl) = pack8(fa[2*c], fa[2*c+1]);
                *(short8*)(Bs + srow * BK + sl) = pack8(fb[2*c], fb[2*c+1]);
            }
        }
        __syncthreads();

        #pragma unroll
        for (int ks = 0; ks < 2; ks++) {
            int q = ks * 4 + quad;
            int sw = (q ^ rlow) * 8;
            short8 af[4], bf[4];
            #pragma unroll
            for (int i = 0; i < 4; i++) {
                af[i] = *(const short8*)(As + (wm + i * 16 + l15) * BK + sw);
                bf[i] = *(const short8*)(Bs + (wn + i * 16 + l15) * BK + sw);
            }
            #pragma unroll
            for (int i = 0; i < 4; i++)
                #pragma unroll
                for (int j = 0; j < 4; j++)
                    acc[i][j] = __builtin_amdgcn_mfma_f32_16x16x32_bf16(
                        af[i], bf[j], acc[i][j], 0, 0, 0);
        }
        __syncthreads();
    }

    long long row0 = (long long)pid_m * BM + wm;
    int col0 = pid_n * BN + wn;
    #pragma unroll
    for (int j = 0; j < 4; j++) {
        int col = col0 + j * 16 + l15;
        float bjv = bias[col];
        #pragma unroll
        for (int i = 0; i < 4; i++) {
            #pragma unroll
            for (int r = 0; r < 4; r++) {
                long long row = row0 + i * 16 + quad * 4 + r;
                C[row * N + col] = acc[i][j][r] + bjv + expect[row];
            }
        }
    }
}

extern "C" void kernel_launch(void* const* d_in, const int* in_sizes, int n_in,
                              void* d_out, int out_size, void* d_ws, size_t ws_size,
                              hipStream_t stream) {
    const float* x = (const float*)d_in[0];   // [8192, 4096] fp32
    const float* W = (const float*)d_in[1];   // [4096, 4096] fp32
    const float* b = (const float*)d_in[2];   // [4096] fp32
    const int*   q = (const int*)d_in[3];     // [8192, 1000] int32
    float* out = (float*)d_out;               // [8192, 4096] fp32

    const int M = 8192, N = 4096, K = 4096, SHOTS = 1000;

    float* expect = (float*)d_ws;             // 32 KB
    size_t need = 32768 + (size_t)M * K * 2 + (size_t)N * K * 2;  // ~96 MB

    if (ws_size >= need) {
        ushort_t* xb = (ushort_t*)((char*)d_ws + 32768);
        ushort_t* wb = xb + (size_t)M * K;
        conv_kernel<<<8192, 256, 0, stream>>>(x, xb);             // 8192*4096 f32
        conv_kernel<<<4096, 256, 0, stream>>>(W, wb);             // 4096*4096 f32
        expect_kernel<<<M / 4, 256, 0, stream>>>(q, expect, M, SHOTS);
        gemm8_kernel<<<(M / 256) * (N / 256), 512, 0, stream>>>(xb, wb, b, expect, out, M, N, K);
    } else {
        expect_kernel<<<M / 4, 256, 0, stream>>>(q, expect, M, SHOTS);
        gemm_f32stage_kernel<<<(M / BM) * (N / BN), 256, 0, stream>>>(x, W, b, expect, out, M, N, K);
    }
}